// Round 7
// baseline (400.123 us; speedup 1.0000x reference)
//
#include <hip/hip_runtime.h>
#include <hip/hip_bf16.h>

#define S_LEN 512
#define HDIM 1024
#define H2 2048

typedef float f32x4 __attribute__((ext_vector_type(4)));
typedef float f32x2 __attribute__((ext_vector_type(2)));
typedef __bf16 bf16x8 __attribute__((ext_vector_type(8)));

// ---------------- K1: e1[b,h] = hidden[b,:] . Wa[h,0:1024] + ba[h]  (f32 exact)
#define E1_PITCH 258
__global__ __launch_bounds__(256) void k_e1(const float* __restrict__ hidden,
                                            const float* __restrict__ Wa,
                                            const float* __restrict__ ba,
                                            float* __restrict__ e1) {
    __shared__ float hsh[64 * E1_PITCH];
    int h = blockIdx.x * 4 + (threadIdx.x >> 6);
    int lane = threadIdx.x & 63;
    const float* wrow = Wa + (size_t)h * H2;  // hidden-half of Wa row
    float acc = 0.f;
    for (int k0 = 0; k0 < HDIM; k0 += 256) {
        __syncthreads();
        for (int idx = threadIdx.x; idx < 4096; idx += 256) {
            int b = idx >> 6, ck = (idx & 63) << 2;
            f32x4 v = *(const f32x4*)(hidden + b * HDIM + k0 + ck);
            f32x2 lo; lo[0] = v[0]; lo[1] = v[1];
            f32x2 hi; hi[0] = v[2]; hi[1] = v[3];
            *(f32x2*)(hsh + b * E1_PITCH + ck) = lo;
            *(f32x2*)(hsh + b * E1_PITCH + ck + 2) = hi;
        }
        __syncthreads();
        const float* wr = wrow + k0;
        const float* hb = hsh + lane * E1_PITCH;
#pragma unroll 8
        for (int kk = 0; kk < 256; kk += 4) {
            f32x4 w = *(const f32x4*)(wr + kk);
            f32x2 h01 = *(const f32x2*)(hb + kk);
            f32x2 h23 = *(const f32x2*)(hb + kk + 2);
            acc += w[0] * h01[0] + w[1] * h01[1] + w[2] * h23[0] + w[3] * h23[1];
        }
    }
    e1[lane * HDIM + h] = acc + ba[h];
}

// ---------------- K2: pack Wa2 (f32) -> bf16 BK=32 tiles (R2 layout) + zero ----
// Tile (nt,kt): 128 rows x 4 slots of 16B; chunk (row,slot) holds source cols
// ((slot ^ ((row>>1)&3)) * 8 ..). Linear chunk order = gload_lds dest order.
__global__ __launch_bounds__(256) void k_packB(const float* __restrict__ Wa,
                                               unsigned short* __restrict__ wsB,
                                               float* __restrict__ logits) {
    int ci = blockIdx.x * 256 + threadIdx.x;      // 16B chunk id, 0..131071
    if (ci < S_LEN * 64) logits[ci] = 0.f;        // fused zero (32768 floats)
    int tile = ci >> 9;
    int wi = ci & 511;
    int row = wi >> 2;
    int slot = wi & 3;
    int nt = tile >> 5, kt = tile & 31;
    int n = nt * 128 + row;
    int kk = kt * 32 + ((slot ^ ((row >> 1) & 3)) << 3);
    const float* src = Wa + (size_t)n * H2 + HDIM + kk;  // encoder half
    f32x4 a = *(const f32x4*)src;
    f32x4 b = *(const f32x4*)(src + 4);
    bf16x8 o;
    o[0] = (__bf16)a[0]; o[1] = (__bf16)a[1]; o[2] = (__bf16)a[2]; o[3] = (__bf16)a[3];
    o[4] = (__bf16)b[0]; o[5] = (__bf16)b[1]; o[6] = (__bf16)b[2]; o[7] = (__bf16)b[3];
    *(bf16x8*)(wsB + (size_t)ci * 8) = o;
}

// ---------------- K2b: pack enc (f32) -> bf16 tiles, same layout, per (mt,kt) ----
__global__ __launch_bounds__(256) void k_packA(const float* __restrict__ enc,
                                               unsigned short* __restrict__ wsA) {
    int ci = blockIdx.x * 256 + threadIdx.x;      // 0..4194303 source 32B chunks
    const float* src = enc + (size_t)ci * 8;
    f32x4 a = *(const f32x4*)src;
    f32x4 b = *(const f32x4*)(src + 4);
    int row_g = ci >> 7;          // global row 0..32767
    int cchunk = ci & 127;        // 8-float chunk within row
    int kt = cchunk >> 2, slot_src = cchunk & 3;
    int mt = row_g >> 7, row = row_g & 127;
    int slot = slot_src ^ ((row >> 1) & 3);
    size_t dst = ((((size_t)(mt * 32 + kt)) << 9) + (row << 2) + slot) << 3;  // elems
    bf16x8 o;
    o[0] = (__bf16)a[0]; o[1] = (__bf16)a[1]; o[2] = (__bf16)a[2]; o[3] = (__bf16)a[3];
    o[4] = (__bf16)b[0]; o[5] = (__bf16)b[1]; o[6] = (__bf16)b[2]; o[7] = (__bf16)b[3];
    *(bf16x8*)(wsA + dst) = o;
}

// ---------------- K3: fused GEMM (bf16) + relu + Ws-dot -> atomic logits
// 128x128 tile, BK=32, R2 data path + counted-vmcnt schedule:
// 3 LDS buffers (48KB, 3 blocks/CU); stage(kt+2) issued at top of compute(kt);
// ONE raw s_barrier per K-tile; vmcnt(4) before it (stage(kt+2)'s 4 loads stay
// in flight across the barrier -> never drain to 0 in-loop).
__global__ __launch_bounds__(256, 4) void k_main(const unsigned short* __restrict__ wsA,
                                                 const unsigned short* __restrict__ wsB,
                                                 const float* __restrict__ e1,
                                                 const float* __restrict__ Ws,
                                                 float* __restrict__ logits) {
    __shared__ __align__(16) unsigned short As[3][4096];  // 3 x [128][32] bf16
    __shared__ __align__(16) unsigned short Bs[3][4096];

    int i = blockIdx.x;
    // XCD-aware: the 8 n-blocks sharing an A-panel land on one XCD.
    int mt = ((i >> 6) << 3) | (i & 7);
    int nt = (i >> 3) & 7;
    int r0 = mt * 128;
    int n0 = nt * 128;

    int tid = threadIdx.x;
    int lane = tid & 63, wid = tid >> 6;
    int wr = wid >> 1, wc = wid & 1;
    int c = lane & 15, g = lane >> 4;

    const unsigned short* abase = wsA + ((size_t)(mt * 32) << 12);
    const unsigned short* bbase = wsB + ((size_t)(nt * 32) << 12);

    f32x4 acc[4][4] = {};

#define STAGE(BUF, KT)                                                                   \
    {                                                                                    \
        const unsigned short* as_ = abase + ((size_t)(KT) << 12);                        \
        const unsigned short* bs_ = bbase + ((size_t)(KT) << 12);                        \
        __builtin_amdgcn_global_load_lds(                                                \
            (const __attribute__((address_space(1))) void*)(as_ + (size_t)tid * 8),      \
            (__attribute__((address_space(3))) void*)((char*)As[BUF] + wid * 1024), 16, 0, 0); \
        __builtin_amdgcn_global_load_lds(                                                \
            (const __attribute__((address_space(1))) void*)(as_ + (size_t)(tid + 256) * 8), \
            (__attribute__((address_space(3))) void*)((char*)As[BUF] + 4096 + wid * 1024), 16, 0, 0); \
        __builtin_amdgcn_global_load_lds(                                                \
            (const __attribute__((address_space(1))) void*)(bs_ + (size_t)tid * 8),      \
            (__attribute__((address_space(3))) void*)((char*)Bs[BUF] + wid * 1024), 16, 0, 0); \
        __builtin_amdgcn_global_load_lds(                                                \
            (const __attribute__((address_space(1))) void*)(bs_ + (size_t)(tid + 256) * 8), \
            (__attribute__((address_space(3))) void*)((char*)Bs[BUF] + 4096 + wid * 1024), 16, 0, 0); \
    }

    // ---- prologue: stage tiles 0,1 into bufs 0,1; wait tile 0 only (vmcnt(4))
    STAGE(0, 0);
    STAGE(1, 1);
    __builtin_amdgcn_sched_barrier(0);
    asm volatile("s_waitcnt vmcnt(4)" ::: "memory");
    __builtin_amdgcn_sched_barrier(0);
    __builtin_amdgcn_s_barrier();
    __builtin_amdgcn_sched_barrier(0);

    for (int kt = 0; kt < 32; ++kt) {
        int cur = kt % 3;
        int nxt = (kt + 2) % 3;
        int ks = (kt + 2 < 32) ? kt + 2 : 31;   // dummy re-stage keeps vmcnt uniform

        STAGE(nxt, ks);
        __builtin_amdgcn_sched_barrier(0);

        // --- fragments from buf cur + MFMA
        bf16x8 af[4], bfr[4];
#pragma unroll
        for (int m = 0; m < 4; ++m) {
            int row = wr * 64 + m * 16 + c;
            int slot = g ^ ((row >> 1) & 3);
            af[m] = *(const bf16x8*)((const char*)As[cur] + row * 64 + slot * 16);
        }
#pragma unroll
        for (int n = 0; n < 4; ++n) {
            int rowb = wc * 64 + n * 16 + c;
            int slot = g ^ ((rowb >> 1) & 3);
            bfr[n] = *(const bf16x8*)((const char*)Bs[cur] + rowb * 64 + slot * 16);
        }
        __builtin_amdgcn_s_setprio(1);
#pragma unroll
        for (int m = 0; m < 4; ++m)
#pragma unroll
            for (int n = 0; n < 4; ++n)
                acc[m][n] = __builtin_amdgcn_mfma_f32_16x16x32_bf16(af[m], bfr[n], acc[m][n], 0, 0, 0);
        __builtin_amdgcn_s_setprio(0);
        __builtin_amdgcn_sched_barrier(0);

        // drain stage(kt+1) (oldest 4); stage(kt+2)'s 4 stay in flight
        asm volatile("s_waitcnt vmcnt(4)" ::: "memory");
        __builtin_amdgcn_sched_barrier(0);
        __builtin_amdgcn_s_barrier();
        __builtin_amdgcn_sched_barrier(0);
    }
    // drain dummy stages before epilogue/exit (LDS writes must land while this
    // block still owns the LDS)
    asm volatile("s_waitcnt vmcnt(0)" ::: "memory");
#undef STAGE

    // --- epilogue: v = relu(acc + e1[b,h]); p = v . Ws; atomicAdd into logits
    float wsv[4];
#pragma unroll
    for (int n = 0; n < 4; ++n) wsv[n] = Ws[n0 + wc * 64 + n * 16 + c];

#pragma unroll
    for (int m = 0; m < 4; ++m) {
#pragma unroll
        for (int j = 0; j < 4; ++j) {
            int rl = wr * 64 + m * 16 + g * 4 + j;
            int r = r0 + rl;
            int b = r & 63, sidx = r >> 6;
            const float* e1b = e1 + b * HDIM + n0 + wc * 64;
            float pp = 0.f;
#pragma unroll
            for (int n = 0; n < 4; ++n) {
                float v = acc[m][n][j] + e1b[n * 16 + c];
                v = fmaxf(v, 0.f);
                pp += v * wsv[n];
            }
            pp += __shfl_xor(pp, 1);
            pp += __shfl_xor(pp, 2);
            pp += __shfl_xor(pp, 4);
            pp += __shfl_xor(pp, 8);
            if (c == 0) atomicAdd(&logits[b * S_LEN + sidx], pp);
        }
    }
}

// ---------------- K4: logits -> softmax probs, in place on d_out ----------------
__global__ __launch_bounds__(512) void k_softmax(float* __restrict__ out,
                                                 const float* __restrict__ pe,
                                                 const int* __restrict__ mask,
                                                 float scale) {
    __shared__ float red[8];
    int b = blockIdx.x, s = threadIdx.x;
    int idx = (b << 9) + s;
    float acc = out[idx];
    float logit = (mask[idx] != 0) ? -1e12f : (scale * acc + pe[idx]);
    float m = logit;
#pragma unroll
    for (int o = 32; o >= 1; o >>= 1) m = fmaxf(m, __shfl_xor(m, o));
    if ((s & 63) == 0) red[s >> 6] = m;
    __syncthreads();
    float m2 = red[0];
#pragma unroll
    for (int i2 = 1; i2 < 8; ++i2) m2 = fmaxf(m2, red[i2]);
    float e = expf(logit - m2);
    float t = e;
#pragma unroll
    for (int o = 32; o >= 1; o >>= 1) t += __shfl_xor(t, o);
    __syncthreads();
    if ((s & 63) == 0) red[s >> 6] = t;
    __syncthreads();
    float tot = 0.f;
#pragma unroll
    for (int i2 = 0; i2 < 8; ++i2) tot += red[i2];
    out[idx] = e / tot;
}

extern "C" void kernel_launch(void* const* d_in, const int* in_sizes, int n_in,
                              void* d_out, int out_size, void* d_ws, size_t ws_size,
                              hipStream_t stream) {
    const float* hidden = (const float*)d_in[0];
    const float* enc    = (const float*)d_in[1];
    const float* pe     = (const float*)d_in[2];
    const int*   mask   = (const int*)d_in[3];
    const float* Wa     = (const float*)d_in[4];
    const float* ba     = (const float*)d_in[5];
    const float* Ws     = (const float*)d_in[6];
    float* out = (float*)d_out;

    float* e1 = (float*)d_ws;                                       // 256 KB
    unsigned short* wsB = (unsigned short*)((char*)d_ws + 262144);  // 2 MB
    unsigned short* wsA = (unsigned short*)((char*)d_ws + 262144 + 2097152);  // 64 MB

    const float scale = 0.19494764453248462f;  // log(512)/sqrt(1024)

    k_e1<<<256, 256, 0, stream>>>(hidden, Wa, ba, e1);
    k_packB<<<512, 256, 0, stream>>>(Wa, wsB, out);
    k_packA<<<16384, 256, 0, stream>>>(enc, wsA);
    k_main<<<2048, 256, 0, stream>>>(wsA, wsB, e1, Ws, out);
    k_softmax<<<64, 512, 0, stream>>>(out, pe, mask, scale);
}